// Round 1
// baseline (349.148 us; speedup 1.0000x reference)
//
#include <hip/hip_runtime.h>
#include <math.h>

// ---------------------------------------------------------------------------
// GCN encoder:
//   h0 = x @ W1                         [N,64]
//   h  = relu(LN(agg(h0) + b1))         (agg = sym-normalized adj w/ self loop)
//   out2 = sigmoid(h @ W3 + b3)         [N,6]
//   h2 = h @ W2                         [N,64]
//   out1 = agg(h2) + b2                 [N,64]
// Aggregation via device-built CSR (no float atomics): degree histogram ->
// scan-free slice alloc (one global atomic counter) -> scatter sources.
// ---------------------------------------------------------------------------

__device__ __forceinline__ float wave_sum(float v) {
#pragma unroll
    for (int off = 32; off > 0; off >>= 1) v += __shfl_xor(v, off, 64);
    return v;
}

__global__ void k_init(int* __restrict__ deg, int* __restrict__ total, int n) {
    int i = blockIdx.x * blockDim.x + threadIdx.x;
    if (i < n) deg[i] = 1;               // self loop
    if (i == 0) *total = 0;
}

__global__ void k_degree(const int* __restrict__ col, int* __restrict__ deg, int E) {
    int e = blockIdx.x * blockDim.x + threadIdx.x;
    if (e < E) atomicAdd(&deg[col[e]], 1);
}

__global__ void k_alloc(const int* __restrict__ deg, float* __restrict__ dinv,
                        int* __restrict__ row_start, int* __restrict__ cursor,
                        int* __restrict__ total, int n) {
    int i = blockIdx.x * blockDim.x + threadIdx.x;
    if (i < n) {
        int d = deg[i];
        dinv[i] = rsqrtf((float)d);
        int cnt = d - 1;                 // edges only (self loop handled analytically)
        int s = atomicAdd(total, cnt);   // wave-scanned by compiler -> 1 atomic/wave
        row_start[i] = s;
        cursor[i] = s;
    }
}

__global__ void k_scatter(const int* __restrict__ row, const int* __restrict__ col,
                          int* __restrict__ cursor, int* __restrict__ csr_src, int E) {
    int e = blockIdx.x * blockDim.x + threadIdx.x;
    if (e < E) {
        int c = col[e];
        int p = atomicAdd(&cursor[c], 1);
        csr_src[p] = row[e];
    }
}

// h0 = x @ W1 : [n,128] x [128,64]. 32-node tile, W1 + padded x-tile in LDS.
__global__ __launch_bounds__(256) void k_gemm1(const float* __restrict__ x,
                                               const float* __restrict__ W1,
                                               float* __restrict__ h0, int n) {
    __shared__ float xs[32 * 129];       // +1 pad: bank = (i + k) % 32, conflict-free
    __shared__ float ws[128 * 64];
    int tid = threadIdx.x;
    int node0 = blockIdx.x * 32;
    for (int i = tid; i < 128 * 64; i += 256) ws[i] = W1[i];
    for (int idx = tid; idx < 32 * 128; idx += 256) {
        int r = idx >> 7, k = idx & 127;
        int node = node0 + r;
        xs[r * 129 + k] = (node < n) ? x[node * 128 + k] : 0.f;
    }
    __syncthreads();
    int i = tid & 31;                    // node in tile
    int j0 = (tid >> 5) * 8;             // 8 output cols per thread
    float acc[8];
#pragma unroll
    for (int j = 0; j < 8; j++) acc[j] = 0.f;
    for (int k = 0; k < 128; k++) {
        float a = xs[i * 129 + k];
        const float4* wr = (const float4*)(&ws[k * 64 + j0]);
        float4 w0 = wr[0], w1 = wr[1];
        acc[0] = fmaf(a, w0.x, acc[0]);
        acc[1] = fmaf(a, w0.y, acc[1]);
        acc[2] = fmaf(a, w0.z, acc[2]);
        acc[3] = fmaf(a, w0.w, acc[3]);
        acc[4] = fmaf(a, w1.x, acc[4]);
        acc[5] = fmaf(a, w1.y, acc[5]);
        acc[6] = fmaf(a, w1.z, acc[6]);
        acc[7] = fmaf(a, w1.w, acc[7]);
    }
    int node = node0 + i;
    if (node < n) {
        float4* o = (float4*)(&h0[node * 64 + j0]);
        o[0] = make_float4(acc[0], acc[1], acc[2], acc[3]);
        o[1] = make_float4(acc[4], acc[5], acc[6], acc[7]);
    }
}

// conv1 + bias + LN + ReLU + out2 (h@W3) + h2 (h@W2). One wave per node.
__global__ __launch_bounds__(256) void k_conv1_fused(
    const float* __restrict__ h0, const int* __restrict__ csr_src,
    const int* __restrict__ row_start, const int* __restrict__ deg,
    const float* __restrict__ dinv, const float* __restrict__ b1,
    const float* __restrict__ lnw_g, const float* __restrict__ lnb_g,
    const float* __restrict__ W2, const float* __restrict__ W3,
    const float* __restrict__ b3, float* __restrict__ h2,
    float* __restrict__ out2, int n) {
    __shared__ float sW2[64 * 64];
    int tid = threadIdx.x;
    for (int i = tid; i < 64 * 64; i += 256) sW2[i] = W2[i];
    __syncthreads();
    int lane = tid & 63;
    int node = blockIdx.x * 4 + (tid >> 6);
    if (node >= n) return;

    float dc = dinv[node];
    float self = h0[node * 64 + lane];
    int start = row_start[node];
    int cnt = deg[node] - 1;
    float inner = 0.f;
    int j = 0;
    for (; j + 3 < cnt; j += 4) {        // batch loads for MLP
        int r0 = csr_src[start + j + 0];
        int r1 = csr_src[start + j + 1];
        int r2 = csr_src[start + j + 2];
        int r3 = csr_src[start + j + 3];
        float w0 = dinv[r0], w1 = dinv[r1], w2 = dinv[r2], w3 = dinv[r3];
        float v0 = h0[r0 * 64 + lane], v1 = h0[r1 * 64 + lane];
        float v2 = h0[r2 * 64 + lane], v3 = h0[r3 * 64 + lane];
        inner += w0 * v0 + w1 * v1 + w2 * v2 + w3 * v3;
    }
    for (; j < cnt; j++) {
        int r = csr_src[start + j];
        inner += dinv[r] * h0[r * 64 + lane];
    }
    float val = dc * (dc * self + inner) + b1[lane];

    // LayerNorm over the 64 features (= this wave) + ReLU
    float mu = wave_sum(val) * (1.f / 64.f);
    float d = val - mu;
    float var = wave_sum(d * d) * (1.f / 64.f);
    float y = d * rsqrtf(var + 1e-5f) * lnw_g[lane] + lnb_g[lane];
    y = fmaxf(y, 0.f);

    // out2 = sigmoid(y @ W3 + b3), W3 is [64,6]
    float o2 = 0.f;
#pragma unroll
    for (int m = 0; m < 6; m++) {
        float s = wave_sum(y * W3[lane * 6 + m]);
        if (lane == m) o2 = s;
    }
    if (lane < 6) out2[node * 6 + lane] = 1.f / (1.f + __expf(-(o2 + b3[lane])));

    // h2 = y @ W2 via broadcast-shuffle against LDS-staged W2
    float acc2 = 0.f;
#pragma unroll 8
    for (int k = 0; k < 64; k++) {
        float hk = __shfl(y, k, 64);
        acc2 = fmaf(hk, sW2[k * 64 + lane], acc2);
    }
    h2[node * 64 + lane] = acc2;
}

// conv2: out1 = agg(h2) + b2. One wave per node.
__global__ __launch_bounds__(256) void k_conv2(
    const float* __restrict__ h2, const int* __restrict__ csr_src,
    const int* __restrict__ row_start, const int* __restrict__ deg,
    const float* __restrict__ dinv, const float* __restrict__ b2,
    float* __restrict__ out1, int n) {
    int tid = threadIdx.x;
    int lane = tid & 63;
    int node = blockIdx.x * 4 + (tid >> 6);
    if (node >= n) return;
    float dc = dinv[node];
    float self = h2[node * 64 + lane];
    int start = row_start[node];
    int cnt = deg[node] - 1;
    float inner = 0.f;
    int j = 0;
    for (; j + 3 < cnt; j += 4) {
        int r0 = csr_src[start + j + 0];
        int r1 = csr_src[start + j + 1];
        int r2 = csr_src[start + j + 2];
        int r3 = csr_src[start + j + 3];
        float w0 = dinv[r0], w1 = dinv[r1], w2 = dinv[r2], w3 = dinv[r3];
        float v0 = h2[r0 * 64 + lane], v1 = h2[r1 * 64 + lane];
        float v2 = h2[r2 * 64 + lane], v3 = h2[r3 * 64 + lane];
        inner += w0 * v0 + w1 * v1 + w2 * v2 + w3 * v3;
    }
    for (; j < cnt; j++) {
        int r = csr_src[start + j];
        inner += dinv[r] * h2[r * 64 + lane];
    }
    out1[node * 64 + lane] = dc * (dc * self + inner) + b2[lane];
}

extern "C" void kernel_launch(void* const* d_in, const int* in_sizes, int n_in,
                              void* d_out, int out_size, void* d_ws, size_t ws_size,
                              hipStream_t stream) {
    const float* x   = (const float*)d_in[0];
    const int*   ei  = (const int*)d_in[1];   // [2,E] int32 on device
    const float* W1  = (const float*)d_in[2];
    const float* b1  = (const float*)d_in[3];
    const float* lnw = (const float*)d_in[4];
    const float* lnb = (const float*)d_in[5];
    const float* W2  = (const float*)d_in[6];
    const float* b2  = (const float*)d_in[7];
    const float* W3  = (const float*)d_in[8];
    const float* b3  = (const float*)d_in[9];

    int n = in_sizes[0] / 128;
    int E = in_sizes[1] / 2;
    const int* row = ei;        // sources
    const int* col = ei + E;    // targets

    char* ws = (char*)d_ws;
    size_t off = 0;
    auto carve = [&](size_t bytes) -> char* {
        char* p = ws + off;
        off = (off + bytes + 255) & ~(size_t)255;
        return p;
    };
    int*   deg       = (int*)carve(4 * (size_t)n);
    float* dinv      = (float*)carve(4 * (size_t)n);
    int*   row_start = (int*)carve(4 * (size_t)n);
    int*   cursor    = (int*)carve(4 * (size_t)n);
    int*   total     = (int*)carve(4);
    int*   csr       = (int*)carve(4 * (size_t)E);
    float* h0        = (float*)carve(256 * (size_t)n);
    float* h2        = (float*)carve(256 * (size_t)n);

    float* out1 = (float*)d_out;
    float* out2 = out1 + (size_t)n * 64;

    k_init<<<(n + 255) / 256, 256, 0, stream>>>(deg, total, n);
    k_degree<<<(E + 255) / 256, 256, 0, stream>>>(col, deg, E);
    k_alloc<<<(n + 255) / 256, 256, 0, stream>>>(deg, dinv, row_start, cursor, total, n);
    k_scatter<<<(E + 255) / 256, 256, 0, stream>>>(row, col, cursor, csr, E);
    k_gemm1<<<(n + 31) / 32, 256, 0, stream>>>(x, W1, h0, n);
    k_conv1_fused<<<(n + 3) / 4, 256, 0, stream>>>(h0, csr, row_start, deg, dinv,
                                                   b1, lnw, lnb, W2, W3, b3,
                                                   h2, out2, n);
    k_conv2<<<(n + 3) / 4, 256, 0, stream>>>(h2, csr, row_start, deg, dinv, b2,
                                             out1, n);
}

// Round 2
// 325.482 us; speedup vs baseline: 1.0727x; 1.0727x over previous
//
#include <hip/hip_runtime.h>
#include <hip/hip_fp16.h>
#include <math.h>

// ---------------------------------------------------------------------------
// GCN encoder, gather-based aggregation over device-built CSR.
// Key trick: aggregation sources are stored PRE-SCALED in fp16:
//   hs[r]  = dinv[r] * h0[r]   ->  conv1:  val = dc * sum(hs[nbrs+self]) + b1
//   h2s[r] = dinv[r] * h2[r]   ->  conv2:  out1 = dc * sum(h2s[nbrs+self]) + b2
// (self loop folds in because dc^2*h = dc*(dinv*h)). 128 B rows, gathered by
// 32 lanes x 4 B (2 edges per wave instruction, 8 edges in flight).
// ---------------------------------------------------------------------------

__device__ __forceinline__ float wave_sum(float v) {
#pragma unroll
    for (int off = 32; off > 0; off >>= 1) v += __shfl_xor(v, off, 64);
    return v;
}

__global__ void k_init(int* __restrict__ deg, int* __restrict__ total, int n) {
    int i = blockIdx.x * blockDim.x + threadIdx.x;
    if (i < n) deg[i] = 1;               // self loop
    if (i == 0) *total = 0;
}

__global__ void k_degree(const int* __restrict__ col, int* __restrict__ deg, int E) {
    int e = blockIdx.x * blockDim.x + threadIdx.x;
    if (e < E) atomicAdd(&deg[col[e]], 1);
}

__global__ void k_alloc(const int* __restrict__ deg, float* __restrict__ dinv,
                        int* __restrict__ row_start, int* __restrict__ cursor,
                        int* __restrict__ total, int n) {
    int i = blockIdx.x * blockDim.x + threadIdx.x;
    if (i < n) {
        int d = deg[i];
        dinv[i] = rsqrtf((float)d);
        int cnt = d - 1;                 // edges only
        int s = atomicAdd(total, cnt);   // compiler wave-scans -> 1 atomic/wave
        row_start[i] = s;
        cursor[i] = s;
    }
}

__global__ void k_scatter(const int* __restrict__ row, const int* __restrict__ col,
                          int* __restrict__ cursor, int* __restrict__ csr_src, int E) {
    int e = blockIdx.x * blockDim.x + threadIdx.x;
    if (e < E) {
        int c = col[e];
        int p = atomicAdd(&cursor[c], 1);
        csr_src[p] = row[e];
    }
}

// hs = (x @ W1) * dinv[node], stored fp16 packed as uint (2 feats per uint).
__global__ __launch_bounds__(256) void k_gemm1(const float* __restrict__ x,
                                               const float* __restrict__ W1,
                                               const float* __restrict__ dinv,
                                               uint* __restrict__ hs, int n) {
    __shared__ float xs[32 * 129];       // +1 pad: conflict-free
    __shared__ float ws[128 * 64];
    int tid = threadIdx.x;
    int node0 = blockIdx.x * 32;
    for (int i = tid; i < 128 * 64; i += 256) ws[i] = W1[i];
    for (int idx = tid; idx < 32 * 128; idx += 256) {
        int r = idx >> 7, k = idx & 127;
        int node = node0 + r;
        xs[r * 129 + k] = (node < n) ? x[node * 128 + k] : 0.f;
    }
    __syncthreads();
    int i = tid & 31;                    // node in tile
    int j0 = (tid >> 5) * 8;             // 8 output cols per thread
    float acc[8];
#pragma unroll
    for (int j = 0; j < 8; j++) acc[j] = 0.f;
    for (int k = 0; k < 128; k++) {
        float a = xs[i * 129 + k];
        const float4* wr = (const float4*)(&ws[k * 64 + j0]);
        float4 w0 = wr[0], w1 = wr[1];
        acc[0] = fmaf(a, w0.x, acc[0]);
        acc[1] = fmaf(a, w0.y, acc[1]);
        acc[2] = fmaf(a, w0.z, acc[2]);
        acc[3] = fmaf(a, w0.w, acc[3]);
        acc[4] = fmaf(a, w1.x, acc[4]);
        acc[5] = fmaf(a, w1.y, acc[5]);
        acc[6] = fmaf(a, w1.z, acc[6]);
        acc[7] = fmaf(a, w1.w, acc[7]);
    }
    int node = node0 + i;
    if (node < n) {
        float s = dinv[node];
        uint* o = hs + (size_t)node * 32 + (j0 >> 1);
#pragma unroll
        for (int t = 0; t < 4; t++) {
            __half2 p = __floats2half2_rn(s * acc[2 * t], s * acc[2 * t + 1]);
            o[t] = *(uint*)&p;
        }
    }
}

// conv1 + bias + LN + ReLU + out2 (h@W3) + h2s (= dinv * (h@W2), fp16).
// One wave per node; 32 lanes per row; 2 edges/instr; 8 edges in flight.
__global__ __launch_bounds__(256) void k_conv1_fused(
    const uint* __restrict__ hs, const int* __restrict__ csr_src,
    const int* __restrict__ row_start, const int* __restrict__ deg,
    const float* __restrict__ dinv, const float* __restrict__ b1,
    const float* __restrict__ lnw_g, const float* __restrict__ lnb_g,
    const float* __restrict__ W2, const float* __restrict__ W3,
    const float* __restrict__ b3, uint* __restrict__ h2s,
    float* __restrict__ out2, int n) {
    __shared__ float sW2[64 * 64];
    int tid = threadIdx.x;
    for (int i = tid; i < 64 * 64; i += 256) sW2[i] = W2[i];
    __syncthreads();
    int lane = tid & 63;
    int node = blockIdx.x * 4 + (tid >> 6);
    if (node >= n) return;

    int m = lane & 31;
    int g = lane >> 5;
    int start = row_start[node];
    int cntE = deg[node] - 1;            // real edges
    int cntS = cntE + 1;                 // + folded self loop
    float ax = 0.f, ay = 0.f;
    for (int jb = 0; jb < cntS; jb += 8) {
        int r[4]; float w[4];
#pragma unroll
        for (int t = 0; t < 4; t++) {
            int j = jb + 2 * t + g;
            w[t] = (j < cntS) ? 1.f : 0.f;
            r[t] = (j < cntE) ? csr_src[start + j] : node;
        }
        uint u[4];
#pragma unroll
        for (int t = 0; t < 4; t++) u[t] = hs[(size_t)r[t] * 32 + m];
#pragma unroll
        for (int t = 0; t < 4; t++) {
            float2 f = __half22float2(*(__half2*)&u[t]);
            ax = fmaf(w[t], f.x, ax);
            ay = fmaf(w[t], f.y, ay);
        }
    }
    ax += __shfl_xor(ax, 32, 64);
    ay += __shfl_xor(ay, 32, 64);
    float va = __shfl(ax, lane >> 1, 64);
    float vb = __shfl(ay, lane >> 1, 64);
    float dc = dinv[node];
    float val = dc * ((lane & 1) ? vb : va) + b1[lane];

    // LayerNorm over 64 features (= this wave) + ReLU
    float mu = wave_sum(val) * (1.f / 64.f);
    float d = val - mu;
    float var = wave_sum(d * d) * (1.f / 64.f);
    float y = d * rsqrtf(var + 1e-5f) * lnw_g[lane] + lnb_g[lane];
    y = fmaxf(y, 0.f);

    // out2 = sigmoid(y @ W3 + b3), W3 is [64,6]
    float o2 = 0.f;
#pragma unroll
    for (int mm = 0; mm < 6; mm++) {
        float s = wave_sum(y * W3[lane * 6 + mm]);
        if (lane == mm) o2 = s;
    }
    if (lane < 6) out2[node * 6 + lane] = 1.f / (1.f + __expf(-(o2 + b3[lane])));

    // h2 = y @ W2 via broadcast-shuffle; store dinv-scaled fp16
    float acc2 = 0.f;
#pragma unroll 8
    for (int k = 0; k < 64; k++) {
        float hk = __shfl(y, k, 64);
        acc2 = fmaf(hk, sW2[k * 64 + lane], acc2);
    }
    float nb = __shfl_xor(acc2, 1, 64);  // odd partner's value
    if (!(lane & 1)) {
        __half2 p = __floats2half2_rn(dc * acc2, dc * nb);
        h2s[(size_t)node * 32 + (lane >> 1)] = *(uint*)&p;
    }
}

// conv2: out1 = dc * sum(h2s[nbrs + self]) + b2
__global__ __launch_bounds__(256) void k_conv2(
    const uint* __restrict__ h2s, const int* __restrict__ csr_src,
    const int* __restrict__ row_start, const int* __restrict__ deg,
    const float* __restrict__ dinv, const float* __restrict__ b2,
    float* __restrict__ out1, int n) {
    int tid = threadIdx.x;
    int lane = tid & 63;
    int node = blockIdx.x * 4 + (tid >> 6);
    if (node >= n) return;
    int m = lane & 31;
    int g = lane >> 5;
    int start = row_start[node];
    int cntE = deg[node] - 1;
    int cntS = cntE + 1;
    float ax = 0.f, ay = 0.f;
    for (int jb = 0; jb < cntS; jb += 8) {
        int r[4]; float w[4];
#pragma unroll
        for (int t = 0; t < 4; t++) {
            int j = jb + 2 * t + g;
            w[t] = (j < cntS) ? 1.f : 0.f;
            r[t] = (j < cntE) ? csr_src[start + j] : node;
        }
        uint u[4];
#pragma unroll
        for (int t = 0; t < 4; t++) u[t] = h2s[(size_t)r[t] * 32 + m];
#pragma unroll
        for (int t = 0; t < 4; t++) {
            float2 f = __half22float2(*(__half2*)&u[t]);
            ax = fmaf(w[t], f.x, ax);
            ay = fmaf(w[t], f.y, ay);
        }
    }
    ax += __shfl_xor(ax, 32, 64);
    ay += __shfl_xor(ay, 32, 64);
    if (g == 0) {
        float dc = dinv[node];
        float2 bb = ((const float2*)b2)[m];
        float2 res;
        res.x = fmaf(dc, ax, bb.x);
        res.y = fmaf(dc, ay, bb.y);
        ((float2*)out1)[(size_t)node * 32 + m] = res;
    }
}

extern "C" void kernel_launch(void* const* d_in, const int* in_sizes, int n_in,
                              void* d_out, int out_size, void* d_ws, size_t ws_size,
                              hipStream_t stream) {
    const float* x   = (const float*)d_in[0];
    const int*   ei  = (const int*)d_in[1];
    const float* W1  = (const float*)d_in[2];
    const float* b1  = (const float*)d_in[3];
    const float* lnw = (const float*)d_in[4];
    const float* lnb = (const float*)d_in[5];
    const float* W2  = (const float*)d_in[6];
    const float* b2  = (const float*)d_in[7];
    const float* W3  = (const float*)d_in[8];
    const float* b3  = (const float*)d_in[9];

    int n = in_sizes[0] / 128;
    int E = in_sizes[1] / 2;
    const int* row = ei;        // sources
    const int* col = ei + E;    // targets

    char* ws = (char*)d_ws;
    size_t off = 0;
    auto carve = [&](size_t bytes) -> char* {
        char* p = ws + off;
        off = (off + bytes + 255) & ~(size_t)255;
        return p;
    };
    int*   deg       = (int*)carve(4 * (size_t)n);
    float* dinv      = (float*)carve(4 * (size_t)n);
    int*   row_start = (int*)carve(4 * (size_t)n);
    int*   cursor    = (int*)carve(4 * (size_t)n);
    int*   total     = (int*)carve(4);
    int*   csr       = (int*)carve(4 * (size_t)E);
    uint*  hs        = (uint*)carve(128 * (size_t)n);
    uint*  h2s       = (uint*)carve(128 * (size_t)n);

    float* out1 = (float*)d_out;
    float* out2 = out1 + (size_t)n * 64;

    k_init<<<(n + 255) / 256, 256, 0, stream>>>(deg, total, n);
    k_degree<<<(E + 255) / 256, 256, 0, stream>>>(col, deg, E);
    k_alloc<<<(n + 255) / 256, 256, 0, stream>>>(deg, dinv, row_start, cursor, total, n);
    k_scatter<<<(E + 255) / 256, 256, 0, stream>>>(row, col, cursor, csr, E);
    k_gemm1<<<(n + 31) / 32, 256, 0, stream>>>(x, W1, dinv, hs, n);
    k_conv1_fused<<<(n + 3) / 4, 256, 0, stream>>>(hs, csr, row_start, deg, dinv,
                                                   b1, lnw, lnb, W2, W3, b3,
                                                   h2s, out2, n);
    k_conv2<<<(n + 3) / 4, 256, 0, stream>>>(h2s, csr, row_start, deg, dinv, b2,
                                             out1, n);
}